// Round 2
// 72.603 us; speedup vs baseline: 1.0079x; 1.0079x over previous
//
#include <hip/hip_runtime.h>

// Problem constants (fixed by reference file)
#define IMG 224
#define NP 109                 // (224-8)/2+1 patches per dimension
#define BC 48                  // batch*channels = 16*3
#define NPIX (IMG * IMG)       // 50176
#define TILE 56                // output pixels per tile side (224 = 4*56)
#define QT 28                  // 2x2 quads per tile side
#define PT 31                  // patch rows/cols relevant to one tile
#define XR 68                  // staged x-region rows (56 + 6 halo + 6 over)
#define XC2 34                 // de-interleaved columns (float2 halves)
#define NTHR 512               // R5: 512-thread blocks -> 24 waves/CU (was 12)

// Math: filt zeros DCT coefficients (0,0),(0,1),(1,0) only; D orthonormal =>
// per-patch y = P - c00*D0(x)D0 - c01*D0(x)D1 - c10*D1(x)D0, and the
// scatter-add of P collapses to cnt(h,w)*x[h,w].
//
// R4 structure (separable, shared partials):
//   P1 stage x de-interleaved (xe=even cols, xo=odd cols)   [global->LDS]
//   P2 row partials  s(r,pc)=D0.row, t(r,pc)=D1.row         (68x31, shared 4x)
//   P3 patch coefs   c00,c01,c10 from s,t                   (31x31)
//   P4 row-gather    RSe/RSo/RTe/RTo(pr,qw)                 (31x28, shared 4x)
//   P5 quads: combine 4 row-gathers + identity term         (28x28)
// All LDS reads stride-1 b32 (conflict-free). RS* overlays dead s/t buffer.
//
// R5 change (occupancy): kernel is latency/barrier-bound, all throughput
// floors are <5 us. 256-thread blocks gave exactly 3 blocks/CU = 12 waves/CU.
// 512-thread blocks keep 3 blocks/CU (LDS 46.9KB*3 = 140.7KB < 160KB,
// 1536 thr < 2048/CU) but double resident waves to 24/CU and halve the
// per-thread work between barriers.
// (R6: resubmit of R5 — previous round was an infra failure, kernel never ran.)
//
// CODEGEN RULE (R1): no runtime-indexed private arrays -- all D accesses are
// literal-indexed named scalars via macro unrolling.

#define LOAD_D_SCALARS(D)                                                  \
    const float d0_0 = (D)[0], d0_1 = (D)[1], d0_2 = (D)[2], d0_3 = (D)[3],\
                d0_4 = (D)[4], d0_5 = (D)[5], d0_6 = (D)[6], d0_7 = (D)[7];\
    const float d1_0 = (D)[8],  d1_1 = (D)[9],  d1_2 = (D)[10],            \
                d1_3 = (D)[11], d1_4 = (D)[12], d1_5 = (D)[13],            \
                d1_6 = (D)[14], d1_7 = (D)[15];

// LDS layout (floats)
#define O_XE   0                       // 68*34 = 2312
#define O_XO   (O_XE + XR * XC2)       // 2312
#define O_RS   (O_XO + XR * XC2)       // 68*31 = 2108
#define O_RT   (O_RS + XR * PT)        // 2108
#define O_RSE  O_RS                    // overlays RS/RT after P3 (868 each)
#define O_RSO  (O_RSE + PT * QT)
#define O_RTE  (O_RSO + PT * QT)
#define O_RTO  (O_RTE + PT * QT)
#define O_CA   (O_RT + XR * PT)        // 31*31 = 961
#define O_CB   (O_CA + PT * PT)
#define O_CC   (O_CB + PT * PT)
#define LDS_FLOATS (O_CC + PT * PT)    // 11723 floats = 46.9 KB

__global__ __launch_bounds__(NTHR) void fused_dct_kernel(
    const float* __restrict__ x, const float* __restrict__ D,
    const float* __restrict__ filt, float* __restrict__ out)
{
    __shared__ float lds[LDS_FLOATS];
    float* const xe_s = lds + O_XE;
    float* const xo_s = lds + O_XO;
    float* const rs_s = lds + O_RS;
    float* const rt_s = lds + O_RT;
    float* const ca_s = lds + O_CA;
    float* const cb_s = lds + O_CB;
    float* const cc_s = lds + O_CC;
    float* const RSe  = lds + O_RSE;
    float* const RSo  = lds + O_RSO;
    float* const RTe  = lds + O_RTE;
    float* const RTo  = lds + O_RTO;

    const int tid = threadIdx.x;
    const int h0 = blockIdx.y * TILE;
    const int w0 = blockIdx.x * TILE;
    const int bc = blockIdx.z;

    LOAD_D_SCALARS(D)
    const float w00 = 1.0f - filt[0];      // filt[0][0]
    const float w01 = 1.0f - filt[1];      // filt[0][1]
    const float w10 = 1.0f - filt[8];      // filt[1][0]

    const float* xb = x + (size_t)bc * NPIX;

    // ---- P1: stage x rows [h0-6, h0+61], cols [w0-6, w0+61], de-interleaved
    for (int i = tid; i < XR * XC2; i += NTHR) {
        int r  = i / XC2;
        int c2 = i - r * XC2;
        int gr = h0 - 6 + r;
        int gc = w0 - 6 + 2 * c2;              // even => float2-aligned
        float2 v = make_float2(0.f, 0.f);
        if ((unsigned)gr < (unsigned)IMG && (unsigned)gc < (unsigned)IMG)
            v = *(const float2*)(xb + (size_t)gr * IMG + gc);
        xe_s[r * XC2 + c2] = v.x;
        xo_s[r * XC2 + c2] = v.y;
    }
    __syncthreads();

    // ---- P2: row partials s(r,pc) = D0 . xrow, t(r,pc) = D1 . xrow
    for (int i = tid; i < XR * PT; i += NTHR) {
        int r  = i / PT;
        int pc = i - r * PT;
        int b  = r * XC2 + pc;
        float e0 = xe_s[b],     o0 = xo_s[b];
        float e1 = xe_s[b + 1], o1 = xo_s[b + 1];
        float e2 = xe_s[b + 2], o2 = xo_s[b + 2];
        float e3 = xe_s[b + 3], o3 = xo_s[b + 3];
        float s = fmaf(e0, d0_0, fmaf(o0, d0_1,
                  fmaf(e1, d0_2, fmaf(o1, d0_3,
                  fmaf(e2, d0_4, fmaf(o2, d0_5,
                  fmaf(e3, d0_6, o3 * d0_7)))))));
        float t = fmaf(e0, d1_0, fmaf(o0, d1_1,
                  fmaf(e1, d1_2, fmaf(o1, d1_3,
                  fmaf(e2, d1_4, fmaf(o2, d1_5,
                  fmaf(e3, d1_6, o3 * d1_7)))))));
        rs_s[i] = s;
        rt_s[i] = t;
    }
    __syncthreads();

    // ---- P3: patch coefficients (invalid patches -> 0)
    const int pr0 = (h0 >> 1) - 3;
    const int pc0 = (w0 >> 1) - 3;
    for (int p = tid; p < PT * PT; p += NTHR) {
        int prl = p / PT;
        int pcl = p - prl * PT;
        int b   = (2 * prl) * PT + pcl;
        float c00 = 0.f, c01 = 0.f, c10 = 0.f;
#define P3_ROW(i)                                                              \
        {                                                                      \
            float s = rs_s[b + (i) * PT];                                      \
            float t = rt_s[b + (i) * PT];                                      \
            c00 = fmaf(d0_##i, s, c00);                                        \
            c01 = fmaf(d0_##i, t, c01);                                        \
            c10 = fmaf(d1_##i, s, c10);                                        \
        }
        P3_ROW(0) P3_ROW(1) P3_ROW(2) P3_ROW(3)
        P3_ROW(4) P3_ROW(5) P3_ROW(6) P3_ROW(7)
#undef P3_ROW
        bool valid = ((unsigned)(pr0 + prl) < (unsigned)NP) &&
                     ((unsigned)(pc0 + pcl) < (unsigned)NP);
        float m = valid ? 1.0f : 0.0f;
        ca_s[p] = c00 * w00 * m;
        cb_s[p] = c01 * w01 * m;
        cc_s[p] = c10 * w10 * m;
    }
    __syncthreads();   // also protects RS* overlay of rs/rt

    // ---- P4: row-gather partials over patch columns (shared by 4 quads)
    for (int i = tid; i < PT * QT; i += NTHR) {
        int pr = i / QT;
        int qw = i - pr * QT;
        int b  = pr * PT + qw;
        float se = 0.f, so = 0.f, te = 0.f, to = 0.f;
#define P4_COL(kc, je, jo)                                                     \
        {                                                                      \
            float a = ca_s[b + (kc)];                                          \
            float bb = cb_s[b + (kc)];                                         \
            float c = cc_s[b + (kc)];                                          \
            se = fmaf(a, d0_##je, fmaf(bb, d1_##je, se));                      \
            so = fmaf(a, d0_##jo, fmaf(bb, d1_##jo, so));                      \
            te = fmaf(c, d0_##je, te);                                         \
            to = fmaf(c, d0_##jo, to);                                         \
        }
        P4_COL(0, 6, 7) P4_COL(1, 4, 5) P4_COL(2, 2, 3) P4_COL(3, 0, 1)
#undef P4_COL
        RSe[i] = se; RSo[i] = so; RTe[i] = te; RTo[i] = to;
    }
    __syncthreads();

    // ---- P5: quads — combine 4 row partials + identity term
    const int qh0 = h0 >> 1, qw0 = w0 >> 1;
    float* ob = out + (size_t)bc * NPIX;
    for (int q = tid; q < QT * QT; q += NTHR) {
        int qhl = q / QT;
        int qwl = q - qhl * QT;
        int b   = qhl * QT + qwl;
        float aee = 0.f, aeo = 0.f, aoe = 0.f, aoo = 0.f;
#define P5_ROW(kr, ie, io)                                                     \
        {                                                                      \
            int o = b + (kr) * QT;                                             \
            float se = RSe[o], so = RSo[o], te = RTe[o], to = RTo[o];          \
            aee = fmaf(d0_##ie, se, fmaf(d1_##ie, te, aee));                   \
            aeo = fmaf(d0_##ie, so, fmaf(d1_##ie, to, aeo));                   \
            aoe = fmaf(d0_##io, se, fmaf(d1_##io, te, aoe));                   \
            aoo = fmaf(d0_##io, so, fmaf(d1_##io, to, aoo));                   \
        }
        P5_ROW(0, 6, 7) P5_ROW(1, 4, 5) P5_ROW(2, 2, 3) P5_ROW(3, 0, 1)
#undef P5_ROW

        int qh = qh0 + qhl, qw = qw0 + qwl;
        int nvr = min(qh, NP - 1) - max(qh - 3, 0) + 1;
        int nvc = min(qw, NP - 1) - max(qw - 3, 0) + 1;
        float cnt = (float)(nvr * nvc);

        // identity term: quad pixels at staged rows 2qhl+6, cols 2qwl+6
        int xr = (2 * qhl + 6) * XC2 + (qwl + 3);
        float x00 = xe_s[xr],       x01 = xo_s[xr];
        float x10 = xe_s[xr + XC2], x11 = xo_s[xr + XC2];

        float2 o0, o1;
        o0.x = fmaf(cnt, x00, -aee);
        o0.y = fmaf(cnt, x01, -aeo);
        o1.x = fmaf(cnt, x10, -aoe);
        o1.y = fmaf(cnt, x11, -aoo);

        float* orp = ob + (size_t)(h0 + 2 * qhl) * IMG + (w0 + 2 * qwl);
        *(float2*)orp         = o0;
        *(float2*)(orp + IMG) = o1;
    }
}

extern "C" void kernel_launch(void* const* d_in, const int* in_sizes, int n_in,
                              void* d_out, int out_size, void* d_ws, size_t ws_size,
                              hipStream_t stream)
{
    const float* x    = (const float*)d_in[0];
    const float* D    = (const float*)d_in[1];
    const float* filt = (const float*)d_in[2];
    float* out        = (float*)d_out;

    dim3 grid(IMG / TILE, IMG / TILE, BC);   // 4 x 4 x 48 = 768 workgroups
    fused_dct_kernel<<<grid, NTHR, 0, stream>>>(x, D, filt, out);
    (void)d_ws; (void)ws_size;               // workspace intentionally unused
}